// Round 3
// baseline (116.286 us; speedup 1.0000x reference)
//
#include <hip/hip_runtime.h>

#define DIM    512
#define RANK   64
#define TDIM   1024
#define BB     2
#define NROWS  (BB * TDIM)     // 2048 flattened rows per tensor
#define KSPLIT 4
#define KCH    (DIM / KSPLIT)  // 128 K-columns per proj block

typedef float v4f __attribute__((ext_vector_type(4)));
typedef float v2f __attribute__((ext_vector_type(2)));

__device__ __forceinline__ float fast_exp2(float x) { return __builtin_amdgcn_exp2f(x); }
__device__ __forceinline__ float fast_rcp(float x)  { return __builtin_amdgcn_rcpf(x); }

// ---------------------------------------------------------------------------
// Projection v3 (unchanged from round 2): split-K=4 into 4 SEPARATE buffers.
// grid = (NROWS/32, KSPLIT, 2) = 512 blocks (2/CU, 8 waves/CU).
// RANK-SLOT PERMUTATION: slots {4tx+j} hold logical ranks {tx+16j};
// pair_kernel permutes the weight vectors to match (sum over r invariant).
// ---------------------------------------------------------------------------
__global__ __launch_bounds__(256)
void proj_kernel(const float* __restrict__ tv, const float* __restrict__ sv,
                 const float* __restrict__ Wt, const float* __restrict__ Ws,
                 float* __restrict__ pt, float* __restrict__ ps)
{
    const int which = blockIdx.z;
    const float* X = which ? sv : tv;
    const float* W = which ? Ws : Wt;
    float* P = (which ? ps : pt) + (size_t)blockIdx.y * NROWS * RANK;

    const int row0 = blockIdx.x * 32;
    const int kc   = blockIdx.y * KCH;
    const int tid  = threadIdx.x;
    const int tx   = tid & 15;
    const int ty   = tid >> 4;

    __shared__ float xs[32][132];   // 16.9 KB
    __shared__ float wsm[64][132];  // 33.8 KB

#pragma unroll
    for (int p = 0; p < 4; p++) {
        const int li = p * 256 + tid;
        const int r  = li >> 5;
        const int c  = (li & 31) << 2;
        *(v4f*)&xs[r][c] = *(const v4f*)&X[(size_t)(row0 + r) * DIM + kc + c];
    }
#pragma unroll
    for (int p = 0; p < 8; p++) {
        const int li = p * 256 + tid;
        const int r  = li >> 5;
        const int c  = (li & 31) << 2;
        *(v4f*)&wsm[r][c] = *(const v4f*)&W[(size_t)r * DIM + kc + c];
    }
    __syncthreads();

    float acc[2][4];
#pragma unroll
    for (int i = 0; i < 2; i++)
#pragma unroll
        for (int j = 0; j < 4; j++) acc[i][j] = 0.f;

#pragma unroll 4
    for (int k4 = 0; k4 < KCH; k4 += 4) {
        v4f a[2], b[4];
#pragma unroll
        for (int i = 0; i < 2; i++)
            a[i] = *(const v4f*)&xs[ty + 16 * i][k4];   // broadcast per 16-group
#pragma unroll
        for (int j = 0; j < 4; j++)
            b[j] = *(const v4f*)&wsm[tx + 16 * j][k4];  // 2-way bank: free
#pragma unroll
        for (int i = 0; i < 2; i++)
#pragma unroll
            for (int j = 0; j < 4; j++) {
                acc[i][j] = fmaf(a[i].x, b[j].x, acc[i][j]);
                acc[i][j] = fmaf(a[i].y, b[j].y, acc[i][j]);
                acc[i][j] = fmaf(a[i].z, b[j].z, acc[i][j]);
                acc[i][j] = fmaf(a[i].w, b[j].w, acc[i][j]);
            }
    }

    // slot-permuted vector store: slots 4tx..4tx+3 hold logical ranks tx+16j
#pragma unroll
    for (int i = 0; i < 2; i++) {
        v4f o = {acc[i][0], acc[i][1], acc[i][2], acc[i][3]};
        *(v4f*)&P[(size_t)(row0 + ty + 16 * i) * RANK + tx * 4] = o;
    }
}

// ---------------------------------------------------------------------------
// Pairwise v3: out[b][t][s] = sum_r iw[r]*silu(pt[b,t,r]*ps[b,s,r])
//                             + tl[b,t] + sl[b,s] + bias
// grid = (16, 32, 2) = 1024 blocks (4/CU). Tile 32(t) x 64(s), micro 2x4.
// This round's VALU-slot cuts (trans count unchanged, exp2 irreducible):
//  - pts staged PRE-SCALED by -log2(e): a2 mul removed from inner loop;
//    weight vec compensated by 1/NL2E (exact: wa = pts'*(wv/NL2E)).
//  - packed accumulator: {1/(d0d1),1/(d2d3)}*{uA,uB} = 1 pk_mul + 1 pk_fma
//    (was 2 mul + 2 fma); horizontal add once in epilogue.
//  - bias folded into slsh.
// Per 4 elems: ~15 VALU (8 pk) + 5 trans -> trans-pipe-bound (~8.5 us floor).
// ---------------------------------------------------------------------------
__global__ __launch_bounds__(256)
void pair_kernel(const float* __restrict__ pt, const float* __restrict__ ps,
                 const float* __restrict__ wt_out, const float* __restrict__ ws_out,
                 const float* __restrict__ iw, const float* __restrict__ bias_p,
                 float* __restrict__ out)
{
    const int b  = blockIdx.z;
    const int t0 = blockIdx.y * 32;
    const int s0 = blockIdx.x * 64;
    const int tid = threadIdx.x;
    const int tx  = tid & 15;
    const int ty  = tid >> 4;

    __shared__ float pts[32][68];             // pre-scaled by NL2E
    __shared__ float sts[64][68];
    __shared__ __align__(16) float wsh2[64];  // iw (slot-permuted) / NL2E
    __shared__ float wtsh[64];                // wt_out (slot-permuted) / NL2E
    __shared__ float wssh[64];                // ws_out (slot-permuted), raw
    __shared__ float tlsh[32];
    __shared__ float slsh[64];

    const float NL2E = -1.44269504088896340736f;  // -log2(e)
    const float INV_NL2E = -0.6931471805599453f;  // 1/NL2E = -ln(2)

    const size_t SPL = (size_t)NROWS * RANK;
    const float* ptb = pt + ((size_t)b * TDIM + t0) * RANK;
    const float* psb = ps + ((size_t)b * TDIM + s0) * RANK;

    // ---- stage pt rows (sum 4 K-splits, pre-scale by NL2E) ----
#pragma unroll
    for (int p = 0; p < 2; p++) {
        const int li = p * 256 + tid;
        const int r  = li >> 4;
        const int c  = (li & 15) << 2;
        const float* src = ptb + (size_t)r * RANK + c;
        v4f v = *(const v4f*)src;
        v += *(const v4f*)(src + SPL);
        v += *(const v4f*)(src + 2 * SPL);
        v += *(const v4f*)(src + 3 * SPL);
        *(v4f*)&pts[r][c] = v * NL2E;
    }
    // ---- stage ps rows (raw) ----
#pragma unroll
    for (int p = 0; p < 4; p++) {
        const int li = p * 256 + tid;
        const int r  = li >> 4;
        const int c  = (li & 15) << 2;
        const float* src = psb + (size_t)r * RANK + c;
        v4f v = *(const v4f*)src;
        v += *(const v4f*)(src + SPL);
        v += *(const v4f*)(src + 2 * SPL);
        v += *(const v4f*)(src + 3 * SPL);
        *(v4f*)&sts[r][c] = v;
    }
    if (tid < 64) {
        const int lg = (tid >> 2) + 16 * (tid & 3);  // logical rank of slot tid
        wsh2[tid] = iw[lg] * INV_NL2E;     // wa = pts' * wsh2 = av*iw  (exact)
        wtsh[tid] = wt_out[lg] * INV_NL2E; // tl = sum pts'*wtsh = sum av*wt
        wssh[tid] = ws_out[lg];
    }
    __syncthreads();

    // per-block linear terms (slot-space dot with compensated weights)
    const float bias = bias_p[0];
    if (tid < 32) {
        float v = 0.f;
#pragma unroll 8
        for (int r = 0; r < RANK; r++) v = fmaf(pts[tid][r], wtsh[r], v);
        tlsh[tid] = v;
    } else if (tid >= 64 && tid < 128) {
        const int s = tid - 64;
        float v = bias;
#pragma unroll 8
        for (int r = 0; r < RANK; r++) v = fmaf(sts[s][r], wssh[r], v);
        slsh[s] = v;   // bias folded in
    }
    __syncthreads();

    v2f acc2[2][4];
#pragma unroll
    for (int i = 0; i < 2; i++)
#pragma unroll
        for (int j = 0; j < 4; j++) acc2[i][j] = (v2f){0.f, 0.f};

#pragma unroll 2
    for (int r4 = 0; r4 < RANK; r4 += 4) {
        const v4f w2 = *(const v4f*)&wsh2[r4];
        const v2f w2A = {w2.x, w2.y};
        const v2f w2B = {w2.z, w2.w};

        v2f aA[2], aB[2], nwA[2], nwB[2];
#pragma unroll
        for (int i = 0; i < 2; i++) {
            const v4f av = *(const v4f*)&pts[ty + 16 * i][r4];  // = av_raw*NL2E
            aA[i] = (v2f){av.x, av.y};
            aB[i] = (v2f){av.z, av.w};
            nwA[i] = aA[i] * w2A;   // = av_raw * iw   (pk_mul)
            nwB[i] = aB[i] * w2B;
        }
        v2f bvA[4], bvB[4];
#pragma unroll
        for (int j = 0; j < 4; j++) {
            const v4f bb = *(const v4f*)&sts[tx + 16 * j][r4];  // 2-way bank: free
            bvA[j] = (v2f){bb.x, bb.y};
            bvB[j] = (v2f){bb.z, bb.w};
        }

#pragma unroll
        for (int i = 0; i < 2; i++)
#pragma unroll
            for (int j = 0; j < 4; j++) {
                const v2f tA = aA[i] * bvA[j];          // -z*log2e (pk_mul)
                const v2f tB = aB[i] * bvB[j];
                const float e0 = fast_exp2(tA.x);       // exp(-z)
                const float e1 = fast_exp2(tA.y);
                const float e2 = fast_exp2(tB.x);
                const float e3 = fast_exp2(tB.y);
                v2f dA = {e0, e1};  dA += 1.0f;         // pk_add
                v2f dB = {e2, e3};  dB += 1.0f;
                const v2f nA = nwA[i] * bvA[j];         // w*z (pk_mul)
                const v2f nB = nwB[i] * bvB[j];
                const float uA = fmaf(nA.y, dA.x, nA.x * dA.y);
                const float uB = fmaf(nB.y, dB.x, nB.x * dB.y);
                const float pA = dA.x * dA.y;
                const float pB = dB.x * dB.y;
                const float r  = fast_rcp(pA * pB);     // one rcp / 4 elems
                const v2f rr = (v2f){pB, pA} * r;       // {1/(d0d1), 1/(d2d3)}
                acc2[i][j] += rr * (v2f){uA, uB};       // pk_fma
            }
    }

    // epilogue (horizontal add + linear terms; bias already in slsh)
#pragma unroll
    for (int i = 0; i < 2; i++) {
        const int t = t0 + ty + 16 * i;
        const float tl = tlsh[ty + 16 * i];
        float* orow = out + ((size_t)b * TDIM + t) * TDIM + s0;
#pragma unroll
        for (int j = 0; j < 4; j++) {
            orow[tx + 16 * j] = (acc2[i][j].x + acc2[i][j].y) + tl + slsh[tx + 16 * j];
        }
    }
}

// ---------------------------------------------------------------------------
extern "C" void kernel_launch(void* const* d_in, const int* in_sizes, int n_in,
                              void* d_out, int out_size, void* d_ws, size_t ws_size,
                              hipStream_t stream)
{
    const float* tv     = (const float*)d_in[0];  // [2,1024,512]
    const float* sv     = (const float*)d_in[1];  // [2,1024,512]
    const float* Wt     = (const float*)d_in[2];  // [64,512]
    const float* Ws     = (const float*)d_in[3];  // [64,512]
    const float* wt_out = (const float*)d_in[4];  // [64]
    const float* ws_out = (const float*)d_in[5];  // [64]
    const float* iw     = (const float*)d_in[6];  // [64]
    const float* bias   = (const float*)d_in[7];  // scalar
    float* out = (float*)d_out;                   // [2,1024,1024]

    const size_t SPL = (size_t)NROWS * RANK;      // 131072 floats
    float* pt = (float*)d_ws;                     // [KSPLIT][2048][64]
    float* ps = pt + (size_t)KSPLIT * SPL;        // [KSPLIT][2048][64]

    // no memset: every split slot is written exactly once
    dim3 pgrid(NROWS / 32, KSPLIT, 2);            // 512 blocks
    proj_kernel<<<pgrid, 256, 0, stream>>>(tv, sv, Wt, Ws, pt, ps);

    dim3 ggrid(TDIM / 64, TDIM / 32, BB);         // 1024 blocks
    pair_kernel<<<ggrid, 256, 0, stream>>>(pt, ps, wt_out, ws_out, iw, bias, out);
}

// Round 4
// 114.541 us; speedup vs baseline: 1.0152x; 1.0152x over previous
//
#include <hip/hip_runtime.h>

#define DIM    512
#define RANK   64
#define TDIM   1024
#define BB     2
#define NROWS  (BB * TDIM)     // 2048 flattened rows per tensor
#define KSPLIT 4
#define KCH    (DIM / KSPLIT)  // 128 K-columns per proj block

typedef float v4f __attribute__((ext_vector_type(4)));
typedef float v2f __attribute__((ext_vector_type(2)));

__device__ __forceinline__ float fast_exp2(float x) { return __builtin_amdgcn_exp2f(x); }
__device__ __forceinline__ float fast_rcp(float x)  { return __builtin_amdgcn_rcpf(x); }

// ---------------------------------------------------------------------------
// Projection v3 (unchanged): split-K=4 into 4 SEPARATE buffers.
// grid = (NROWS/32, KSPLIT, 2) = 512 blocks (2/CU, 8 waves/CU).
// RANK-SLOT PERMUTATION: slots {4tx+j} hold logical ranks {tx+16j};
// pair_kernel permutes the weight vectors to match (sum over r invariant).
// ---------------------------------------------------------------------------
__global__ __launch_bounds__(256)
void proj_kernel(const float* __restrict__ tv, const float* __restrict__ sv,
                 const float* __restrict__ Wt, const float* __restrict__ Ws,
                 float* __restrict__ pt, float* __restrict__ ps)
{
    const int which = blockIdx.z;
    const float* X = which ? sv : tv;
    const float* W = which ? Ws : Wt;
    float* P = (which ? ps : pt) + (size_t)blockIdx.y * NROWS * RANK;

    const int row0 = blockIdx.x * 32;
    const int kc   = blockIdx.y * KCH;
    const int tid  = threadIdx.x;
    const int tx   = tid & 15;
    const int ty   = tid >> 4;

    __shared__ float xs[32][132];   // 16.9 KB
    __shared__ float wsm[64][132];  // 33.8 KB

#pragma unroll
    for (int p = 0; p < 4; p++) {
        const int li = p * 256 + tid;
        const int r  = li >> 5;
        const int c  = (li & 31) << 2;
        *(v4f*)&xs[r][c] = *(const v4f*)&X[(size_t)(row0 + r) * DIM + kc + c];
    }
#pragma unroll
    for (int p = 0; p < 8; p++) {
        const int li = p * 256 + tid;
        const int r  = li >> 5;
        const int c  = (li & 31) << 2;
        *(v4f*)&wsm[r][c] = *(const v4f*)&W[(size_t)r * DIM + kc + c];
    }
    __syncthreads();

    float acc[2][4];
#pragma unroll
    for (int i = 0; i < 2; i++)
#pragma unroll
        for (int j = 0; j < 4; j++) acc[i][j] = 0.f;

#pragma unroll 4
    for (int k4 = 0; k4 < KCH; k4 += 4) {
        v4f a[2], b[4];
#pragma unroll
        for (int i = 0; i < 2; i++)
            a[i] = *(const v4f*)&xs[ty + 16 * i][k4];   // broadcast per 16-group
#pragma unroll
        for (int j = 0; j < 4; j++)
            b[j] = *(const v4f*)&wsm[tx + 16 * j][k4];  // 2-way bank: free
#pragma unroll
        for (int i = 0; i < 2; i++)
#pragma unroll
            for (int j = 0; j < 4; j++) {
                acc[i][j] = fmaf(a[i].x, b[j].x, acc[i][j]);
                acc[i][j] = fmaf(a[i].y, b[j].y, acc[i][j]);
                acc[i][j] = fmaf(a[i].z, b[j].z, acc[i][j]);
                acc[i][j] = fmaf(a[i].w, b[j].w, acc[i][j]);
            }
    }

    // slot-permuted vector store: slots 4tx..4tx+3 hold logical ranks tx+16j
#pragma unroll
    for (int i = 0; i < 2; i++) {
        v4f o = {acc[i][0], acc[i][1], acc[i][2], acc[i][3]};
        *(v4f*)&P[(size_t)(row0 + ty + 16 * i) * RANK + tx * 4] = o;
    }
}

// ---------------------------------------------------------------------------
// Pairwise v4: occupancy restructure. Tile 32(t) x 32(s), micro 2x2,
// grid = (32, 32, 2) = 2048 blocks -> 8 blocks/CU (thread-cap bound),
// up to 32 waves/CU (was measured 8 waves/CU @ 32x64 tile).
// LDS 18.4 KB/block. Inner math byte-identical to v3 (same packed body,
// 4-way shared reciprocal) -> absmax unchanged; only the quad now covers
// 4 ranks of one (t,s) element instead of 4 s-columns.
// ---------------------------------------------------------------------------
__global__ __launch_bounds__(256)
void pair_kernel(const float* __restrict__ pt, const float* __restrict__ ps,
                 const float* __restrict__ wt_out, const float* __restrict__ ws_out,
                 const float* __restrict__ iw, const float* __restrict__ bias_p,
                 float* __restrict__ out)
{
    const int b  = blockIdx.z;
    const int t0 = blockIdx.y * 32;
    const int s0 = blockIdx.x * 32;
    const int tid = threadIdx.x;
    const int tx  = tid & 15;
    const int ty  = tid >> 4;

    __shared__ float pts[32][68];             // pre-scaled by NL2E
    __shared__ float sts[32][68];
    __shared__ __align__(16) float wsh2[64];  // iw (slot-permuted) / NL2E
    __shared__ float wtsh[64];                // wt_out (slot-permuted) / NL2E
    __shared__ float wssh[64];                // ws_out (slot-permuted), raw
    __shared__ float tlsh[32];
    __shared__ float slsh[32];

    const float NL2E = -1.44269504088896340736f;  // -log2(e)
    const float INV_NL2E = -0.6931471805599453f;  // 1/NL2E = -ln(2)

    const size_t SPL = (size_t)NROWS * RANK;
    const float* ptb = pt + ((size_t)b * TDIM + t0) * RANK;
    const float* psb = ps + ((size_t)b * TDIM + s0) * RANK;

    // ---- stage pt rows (sum 4 K-splits, pre-scale by NL2E): 2 v4f/thread ----
#pragma unroll
    for (int p = 0; p < 2; p++) {
        const int li = p * 256 + tid;
        const int r  = li >> 4;
        const int c  = (li & 15) << 2;
        const float* src = ptb + (size_t)r * RANK + c;
        v4f v = *(const v4f*)src;
        v += *(const v4f*)(src + SPL);
        v += *(const v4f*)(src + 2 * SPL);
        v += *(const v4f*)(src + 3 * SPL);
        *(v4f*)&pts[r][c] = v * NL2E;
    }
    // ---- stage ps rows (raw): 2 v4f/thread ----
#pragma unroll
    for (int p = 0; p < 2; p++) {
        const int li = p * 256 + tid;
        const int r  = li >> 4;
        const int c  = (li & 15) << 2;
        const float* src = psb + (size_t)r * RANK + c;
        v4f v = *(const v4f*)src;
        v += *(const v4f*)(src + SPL);
        v += *(const v4f*)(src + 2 * SPL);
        v += *(const v4f*)(src + 3 * SPL);
        *(v4f*)&sts[r][c] = v;
    }
    if (tid < 64) {
        const int lg = (tid >> 2) + 16 * (tid & 3);  // logical rank of slot tid
        wsh2[tid] = iw[lg] * INV_NL2E;     // wa = pts' * wsh2 = av*iw  (exact)
        wtsh[tid] = wt_out[lg] * INV_NL2E; // tl = sum pts'*wtsh = sum av*wt
        wssh[tid] = ws_out[lg];
    }
    __syncthreads();

    // per-block linear terms (different waves for the two jobs)
    const float bias = bias_p[0];
    if (tid < 32) {
        float v = 0.f;
#pragma unroll 8
        for (int r = 0; r < RANK; r++) v = fmaf(pts[tid][r], wtsh[r], v);
        tlsh[tid] = v;
    } else if (tid >= 64 && tid < 96) {
        const int s = tid - 64;
        float v = bias;
#pragma unroll 8
        for (int r = 0; r < RANK; r++) v = fmaf(sts[s][r], wssh[r], v);
        slsh[s] = v;   // bias folded in
    }
    __syncthreads();

    v2f acc2[2][2];
#pragma unroll
    for (int i = 0; i < 2; i++)
#pragma unroll
        for (int j = 0; j < 2; j++) acc2[i][j] = (v2f){0.f, 0.f};

#pragma unroll 2
    for (int r4 = 0; r4 < RANK; r4 += 4) {
        const v4f w2 = *(const v4f*)&wsh2[r4];
        const v2f w2A = {w2.x, w2.y};
        const v2f w2B = {w2.z, w2.w};

        v2f aA[2], aB[2], nwA[2], nwB[2];
#pragma unroll
        for (int i = 0; i < 2; i++) {
            const v4f av = *(const v4f*)&pts[ty + 16 * i][r4];  // = av_raw*NL2E (broadcast)
            aA[i] = (v2f){av.x, av.y};
            aB[i] = (v2f){av.z, av.w};
            nwA[i] = aA[i] * w2A;   // = av_raw * iw   (pk_mul)
            nwB[i] = aB[i] * w2B;
        }
        v2f bvA[2], bvB[2];
#pragma unroll
        for (int j = 0; j < 2; j++) {
            const v4f bb = *(const v4f*)&sts[tx + 16 * j][r4];  // 2-way bank: free
            bvA[j] = (v2f){bb.x, bb.y};
            bvB[j] = (v2f){bb.z, bb.w};
        }

#pragma unroll
        for (int i = 0; i < 2; i++)
#pragma unroll
            for (int j = 0; j < 2; j++) {
                const v2f tA = aA[i] * bvA[j];          // -z*log2e (pk_mul)
                const v2f tB = aB[i] * bvB[j];
                const float e0 = fast_exp2(tA.x);       // exp(-z)
                const float e1 = fast_exp2(tA.y);
                const float e2 = fast_exp2(tB.x);
                const float e3 = fast_exp2(tB.y);
                v2f dA = {e0, e1};  dA += 1.0f;         // pk_add
                v2f dB = {e2, e3};  dB += 1.0f;
                const v2f nA = nwA[i] * bvA[j];         // w*z (pk_mul)
                const v2f nB = nwB[i] * bvB[j];
                const float uA = fmaf(nA.y, dA.x, nA.x * dA.y);
                const float uB = fmaf(nB.y, dB.x, nB.x * dB.y);
                const float pA = dA.x * dA.y;
                const float pB = dB.x * dB.y;
                const float r  = fast_rcp(pA * pB);     // one rcp / 4 ranks
                const v2f rr = (v2f){pB, pA} * r;       // {1/(d0d1), 1/(d2d3)}
                acc2[i][j] += rr * (v2f){uA, uB};       // pk_fma
            }
    }

    // epilogue (horizontal add + linear terms; bias already in slsh)
#pragma unroll
    for (int i = 0; i < 2; i++) {
        const int t = t0 + ty + 16 * i;
        const float tl = tlsh[ty + 16 * i];
        float* orow = out + ((size_t)b * TDIM + t) * TDIM + s0;
#pragma unroll
        for (int j = 0; j < 2; j++) {
            orow[tx + 16 * j] = (acc2[i][j].x + acc2[i][j].y) + tl + slsh[tx + 16 * j];
        }
    }
}

// ---------------------------------------------------------------------------
extern "C" void kernel_launch(void* const* d_in, const int* in_sizes, int n_in,
                              void* d_out, int out_size, void* d_ws, size_t ws_size,
                              hipStream_t stream)
{
    const float* tv     = (const float*)d_in[0];  // [2,1024,512]
    const float* sv     = (const float*)d_in[1];  // [2,1024,512]
    const float* Wt     = (const float*)d_in[2];  // [64,512]
    const float* Ws     = (const float*)d_in[3];  // [64,512]
    const float* wt_out = (const float*)d_in[4];  // [64]
    const float* ws_out = (const float*)d_in[5];  // [64]
    const float* iw     = (const float*)d_in[6];  // [64]
    const float* bias   = (const float*)d_in[7];  // scalar
    float* out = (float*)d_out;                   // [2,1024,1024]

    const size_t SPL = (size_t)NROWS * RANK;      // 131072 floats
    float* pt = (float*)d_ws;                     // [KSPLIT][2048][64]
    float* ps = pt + (size_t)KSPLIT * SPL;        // [KSPLIT][2048][64]

    // no memset: every split slot is written exactly once
    dim3 pgrid(NROWS / 32, KSPLIT, 2);            // 512 blocks
    proj_kernel<<<pgrid, 256, 0, stream>>>(tv, sv, Wt, Ws, pt, ps);

    dim3 ggrid(TDIM / 32, TDIM / 32, BB);         // 2048 blocks, 8/CU
    pair_kernel<<<ggrid, 256, 0, stream>>>(pt, ps, wt_out, ws_out, iw, bias, out);
}